// Round 5
// baseline (472.515 us; speedup 1.0000x reference)
//
#include <hip/hip_runtime.h>

// MomentumLSTM R5: register-resident weights + 4-wave tiles.
// 1024 blocks x 256 threads; block = one 32-batch tile.
// Waves 0-1: layer-1, each owns h1-units [32w,32w+32) (orig mtiles {w,2+w,4+w,6+w}),
//            Whh1 hi/lo frags (32 x uint4 = 128 VGPR) held in registers.
// Waves 2-3: layer-2 (1-step lag), each owns h2-units [16w,16w+16) via row-permuted
//            mtile pair (i|f and g|o interleaved), Wih2/Whh2 frags (24) in registers.
// L1/L2 register state UNIONED (wreg/acc/cst) so the role branch doesn't double-allocate.
// Hot loop: MFMA operands all-register; only tiny parity-buffered LDS exchange for
// h1 frags, h2 frags, x. Activations use paired-rcp (5 exp + 3 rcp per output).

using f32x16 = __attribute__((ext_vector_type(16))) float;
using s16x8  = __attribute__((ext_vector_type(8)))  short;
using uint2v = __attribute__((ext_vector_type(2)))  unsigned int;
typedef unsigned int uint;
typedef unsigned short ushort;

#define THREADS 256
#define NBLOCKS 1024
#define L2E 1.44269504f

__device__ __forceinline__ float fsig(float v) {
    float e = __builtin_amdgcn_exp2f(-L2E * v);
    return __builtin_amdgcn_rcpf(1.0f + e);
}
// fused LSTM gate block: 5 exp2 + 3 rcp (i,f share a rcp; g,o share a rcp)
__device__ __forceinline__ void lstm_act(float gi, float gf, float gg, float go,
                                         float& cs, float& hv) {
    float ei = __builtin_amdgcn_exp2f(-L2E * gi);
    float ef = __builtin_amdgcn_exp2f(-L2E * gf);
    float eg = __builtin_amdgcn_exp2f((2.0f * L2E) * gg);
    float eo = __builtin_amdgcn_exp2f(-L2E * go);
    float ai = 1.0f + ei, af = 1.0f + ef;
    float r0 = __builtin_amdgcn_rcpf(ai * af);
    float iv = r0 * af, fv = r0 * ai;
    float ag = 1.0f + eg, ao = 1.0f + eo;
    float r1 = __builtin_amdgcn_rcpf(ag * ao);
    float gv = __builtin_fmaf(-2.0f * r1, ao, 1.0f);   // tanh(gg)
    float ov = r1 * ag;                                 // sigmoid(go)
    float c = __builtin_fmaf(fv, cs, iv * gv);
    cs = c;
    float et = __builtin_amdgcn_exp2f((2.0f * L2E) * c);
    float tt = __builtin_fmaf(-2.0f, __builtin_amdgcn_rcpf(1.0f + et), 1.0f);
    hv = ov * tt;
}
__device__ __forceinline__ ushort bfhi(float w) {
    uint u = __builtin_bit_cast(uint, w);
    return (ushort)((u + 0x7fffu + ((u >> 16) & 1u)) >> 16);
}
__device__ __forceinline__ ushort bfpart(float w, int sp) {   // sp0: hi, sp1: lo
    ushort h = bfhi(w);
    if (sp == 0) return h;
    float hf = __builtin_bit_cast(float, (uint)h << 16);
    return bfhi(w - hf);
}
__device__ __forceinline__ uint pkbf(float a, float b) {
    uint r;
    asm("v_cvt_pk_bf16_f32 %0, %1, %2" : "=v"(r) : "v"(a), "v"(b));
    return r;
}
__device__ __forceinline__ uint4 pack8(const ushort v[8]) {
    return make_uint4(v[0] | ((uint)v[1] << 16), v[2] | ((uint)v[3] << 16),
                      v[4] | ((uint)v[5] << 16), v[6] | ((uint)v[7] << 16));
}
#define MFMA32(a, b, c) \
    __builtin_amdgcn_mfma_f32_32x32x16_bf16(__builtin_bit_cast(s16x8, (a)), \
        __builtin_bit_cast(s16x8, (b)), (c), 0, 0, 0)
#define PLSWAP(a, b) __builtin_amdgcn_permlane32_swap((a), (b), false, false)

__global__ void __launch_bounds__(THREADS, 2) lstm_kernel(
    const float* __restrict__ x,
    const float* __restrict__ Wih1, const float* __restrict__ Whh1,
    const float* __restrict__ bih1, const float* __restrict__ bhh1,
    const float* __restrict__ Wih2, const float* __restrict__ Whh2,
    const float* __restrict__ bih2, const float* __restrict__ bhh2,
    const float* __restrict__ Wd, const float* __restrict__ bd,
    const float* __restrict__ Wo, const float* __restrict__ bo,
    float* __restrict__ out)
{
    __shared__ uint4 sXW[2][4][64];   // L1 x-projection frags [w1][g4][lane]
    __shared__ uint4 sH1[2][4][64];   // h1 frag exchange [parity][kt][lane]
    __shared__ uint4 sH2[2][2][64];   // h2 frag exchange [w2][parity][lane]
    __shared__ uint4 sX[2][32];       // packed x [parity][col]
    __shared__ float sWd[512];
    __shared__ float sBd[16], sWo[16], sBo[1];
    __shared__ float sHs[1024];       // head scratch [col][unit]

    const int tid = threadIdx.x;
    const int lane = tid & 63, wave = tid >> 6;
    const int hh = lane >> 5, n = lane & 31;
    const bool isL1 = (wave < 2);
    const int wh = wave & 1;
    const int bbase = blockIdx.x * 32;

    // ---- head weights + zero exchange buffers ----
    for (int i = tid; i < 512; i += THREADS) sWd[i] = Wd[i];
    if (tid < 16) { sBd[tid] = bd[tid]; sWo[tid] = Wo[tid]; }
    if (tid == 0) sBo[0] = bo[0];
    {
        uint4 z = make_uint4(0, 0, 0, 0);
        uint4* zp = &sH1[0][0][0];
        for (int i = tid; i < 512; i += THREADS) zp[i] = z;
        uint4* zq = &sH2[0][0][0];
        for (int i = tid; i < 256; i += THREADS) zq[i] = z;
    }

    // ---- role-shared register state (unioned live ranges) ----
    uint4 wreg[32];                   // L1: Whh1[g4][kt][sp]; L2: Wih2[ms][kt][sp] (0-15), Whh2[ms][kt2][sp] (16-23)
    f32x16 acc[4];                    // L1: C1[g4]; L2: C2[ms] (0-1), bias2 (2-3)
    float  cst[16];                   // L1: c1 x16; L2: c2 x8
    uint4 ho0 = make_uint4(0,0,0,0);  // L1: own h1 frag kt=2wh;   L2: own h2 frag
    uint4 ho1 = make_uint4(0,0,0,0);  // L1: own h1 frag kt=2wh+1
    const float* xp = x + (size_t)(bbase + lane) * 420;

    // ---- stage weights into registers ----
    if (isL1) {
#pragma unroll
        for (int g4 = 0; g4 < 4; ++g4) {
            int row = g4 * 64 + wh * 32 + n;
#pragma unroll
            for (int kt = 0; kt < 4; ++kt) {
                const float* src = Whh1 + row * 64 + kt * 16 + hh * 8;
                float w[8];
#pragma unroll
                for (int e = 0; e < 8; ++e) w[e] = src[e];
#pragma unroll
                for (int sp = 0; sp < 2; ++sp) {
                    ushort v[8];
#pragma unroll
                    for (int e = 0; e < 8; ++e) v[e] = bfpart(w[e], sp);
                    wreg[g4 * 8 + kt * 2 + sp] = pack8(v);
                }
            }
            float b1 = bih1[row] + bhh1[row];
            ushort v[8];
#pragma unroll
            for (int e = 0; e < 8; ++e) {
                float w = (e < 7) ? Wih1[row * 7 + e] : b1;
                v[e] = bfpart(w, hh);                 // hi half-k: hi split; lo half-k: lo split
            }
            sXW[wh][g4][lane] = pack8(v);
        }
    } else {
#pragma unroll
        for (int ms = 0; ms < 2; ++ms) {
            int rho = n;                              // A-frag row
            int G = (ms == 0) ? ((rho < 16) ? wh * 16 + rho : 16 + wh * 16 + rho)
                              : ((rho < 16) ? 64 + wh * 16 + rho : 80 + wh * 16 + rho);
#pragma unroll
            for (int kt = 0; kt < 4; ++kt) {
                const float* src = Wih2 + G * 64 + kt * 16 + hh * 8;
                float w[8];
#pragma unroll
                for (int e = 0; e < 8; ++e) w[e] = src[e];
#pragma unroll
                for (int sp = 0; sp < 2; ++sp) {
                    ushort v[8];
#pragma unroll
                    for (int e = 0; e < 8; ++e) v[e] = bfpart(w[e], sp);
                    wreg[ms * 8 + kt * 2 + sp] = pack8(v);
                }
            }
#pragma unroll
            for (int kt2 = 0; kt2 < 2; ++kt2) {
                const float* src = Whh2 + G * 32 + kt2 * 16 + hh * 8;
                float w[8];
#pragma unroll
                for (int e = 0; e < 8; ++e) w[e] = src[e];
#pragma unroll
                for (int sp = 0; sp < 2; ++sp) {
                    ushort v[8];
#pragma unroll
                    for (int e = 0; e < 8; ++e) v[e] = bfpart(w[e], sp);
                    wreg[16 + ms * 4 + kt2 * 2 + sp] = pack8(v);
                }
            }
#pragma unroll
            for (int r = 0; r < 16; ++r) {            // exact f32 bias in accum-init
                int row = (r & 3) + 8 * (r >> 2) + 4 * hh;
                int Gb = (ms == 0) ? ((row < 16) ? wh * 16 + row : 16 + wh * 16 + row)
                                   : ((row < 16) ? 64 + wh * 16 + row : 80 + wh * 16 + row);
                acc[2 + ms][r] = bih2[Gb] + bhh2[Gb];
            }
        }
        if (wh == 0 && lane < 32) {                   // pack x(0) -> parity 0
            float x0[7];
#pragma unroll
            for (int d = 0; d < 7; ++d) x0[d] = xp[d];
            sX[0][lane] = make_uint4(pkbf(x0[0], x0[1]), pkbf(x0[2], x0[3]),
                                     pkbf(x0[4], x0[5]), pkbf(x0[6], 1.0f));
        }
    }
#pragma unroll
    for (int r = 0; r < 16; ++r) cst[r] = 0.0f;
    __syncthreads();

    f32x16 Z;
#pragma unroll
    for (int i = 0; i < 16; ++i) Z[i] = 0.0f;

    float hv[16];
    uint4 hp0;                                        // L2: partner h2 frag

    // L2 step: computes LSTM-2 step using h1 frags (slot sl1) + h2(prev)
    auto l2step = [&](int sl1, int sl2) {
        uint4 hq[4];
#pragma unroll
        for (int kt = 0; kt < 4; ++kt) hq[kt] = sH1[sl1][kt][lane];
        hp0 = sH2[wh ^ 1][sl2][lane];
#pragma unroll
        for (int ms = 0; ms < 2; ++ms) {
            f32x16 c = acc[2 + ms];
#pragma unroll
            for (int kt = 0; kt < 4; ++kt) {
                c = MFMA32(wreg[ms * 8 + kt * 2 + 0], hq[kt], c);
                c = MFMA32(wreg[ms * 8 + kt * 2 + 1], hq[kt], c);
            }
#pragma unroll
            for (int kt2 = 0; kt2 < 2; ++kt2) {
                uint4 hb = (kt2 == wh) ? ho0 : hp0;
                c = MFMA32(wreg[16 + ms * 4 + kt2 * 2 + 0], hb, c);
                c = MFMA32(wreg[16 + ms * 4 + kt2 * 2 + 1], hb, c);
            }
            acc[ms] = c;
        }
#pragma unroll
        for (int r = 0; r < 8; ++r)
            lstm_act(acc[0][r], acc[0][r + 8], acc[1][r], acc[1][r + 8], cst[r], hv[r]);
        uint Q00 = pkbf(hv[0], hv[1]), Q01 = pkbf(hv[4], hv[5]);
        uint Q10 = pkbf(hv[2], hv[3]), Q11 = pkbf(hv[6], hv[7]);
        uint2v sA = PLSWAP(Q00, Q01);
        uint2v sB = PLSWAP(Q10, Q11);
        ho0 = make_uint4(sA[0], sB[0], sA[1], sB[1]);
    };

    // ---------------- time loop: one barrier per step ----------------
    for (int t = 0; t < 60; ++t) {
        if (isL1) {
            // ===== layer 1, step t =====
            uint4 xB  = sX[t & 1][n];
            uint4 hq0 = sH1[(t + 1) & 1][(wh ^ 1) * 2 + 0][lane];   // partner h1(t-1)
            uint4 hq1 = sH1[(t + 1) & 1][(wh ^ 1) * 2 + 1][lane];
            uint4 xw0 = sXW[wh][0][lane], xw1 = sXW[wh][1][lane];
            uint4 xw2 = sXW[wh][2][lane], xw3 = sXW[wh][3][lane];
#pragma unroll
            for (int g4 = 0; g4 < 4; ++g4) {
                f32x16 c = Z;
#pragma unroll
                for (int kt = 0; kt < 4; ++kt) {
                    uint4 hb = ((kt >> 1) == wh) ? ((kt & 1) ? ho1 : ho0)
                                                 : ((kt & 1) ? hq1 : hq0);
                    c = MFMA32(wreg[g4 * 8 + kt * 2 + 0], hb, c);
                    c = MFMA32(wreg[g4 * 8 + kt * 2 + 1], hb, c);
                }
                uint4 xw = (g4 == 0) ? xw0 : (g4 == 1) ? xw1 : (g4 == 2) ? xw2 : xw3;
                c = MFMA32(xw, xB, c);                // x-proj + bias (hi&lo folded)
                acc[g4] = c;
            }
#pragma unroll
            for (int r = 0; r < 16; ++r)
                lstm_act(acc[0][r], acc[1][r], acc[2][r], acc[3][r], cst[r], hv[r]);
            uint Q0[4], Q1[4];
#pragma unroll
            for (int A = 0; A < 4; ++A) {
                Q0[A] = pkbf(hv[4 * A + 0], hv[4 * A + 1]);
                Q1[A] = pkbf(hv[4 * A + 2], hv[4 * A + 3]);
            }
            {
                uint2v sA = PLSWAP(Q0[0], Q0[1]);
                uint2v sB = PLSWAP(Q1[0], Q1[1]);
                ho0 = make_uint4(sA[0], sB[0], sA[1], sB[1]);
                sH1[t & 1][wh * 2 + 0][lane] = ho0;
            }
            {
                uint2v sA = PLSWAP(Q0[2], Q0[3]);
                uint2v sB = PLSWAP(Q1[2], Q1[3]);
                ho1 = make_uint4(sA[0], sB[0], sA[1], sB[1]);
                sH1[t & 1][wh * 2 + 1][lane] = ho1;
            }
        } else {
            // ===== layer 2, step t-1 =====
            float xr[7];
            if (wh == 0 && lane < 32 && t < 59) {     // prefetch x(t+1)
#pragma unroll
                for (int d = 0; d < 7; ++d) xr[d] = xp[(t + 1) * 7 + d];
            }
            if (t > 0) {
                l2step((t + 1) & 1, t & 1);
                sH2[wh][(t & 1) ^ 1][lane] = ho0;
            }
            if (wh == 0 && lane < 32 && t < 59) {     // pack x(t+1)
                sX[(t + 1) & 1][lane] = make_uint4(pkbf(xr[0], xr[1]), pkbf(xr[2], xr[3]),
                                                   pkbf(xr[4], xr[5]), pkbf(xr[6], 1.0f));
            }
        }
        __syncthreads();
    }

    // ---------------- final L2 step (t=59) + dense head ----------------
    if (!isL1) {
        l2step(1, 0);                                 // h1(59) slot 1, partner h2(58) slot 0
#pragma unroll
        for (int r = 0; r < 8; ++r) {
            int ul = (r & 3) + 8 * (r >> 2) + 4 * hh;
            sHs[n * 32 + wh * 16 + ul] = hv[r];
        }
    }
    __syncthreads();
    if (wave == 2 && lane < 32) {
        const float* hcol = sHs + lane * 32;
        float a[16];
#pragma unroll
        for (int o = 0; o < 16; ++o) a[o] = sBd[o];
#pragma unroll 4
        for (int u = 0; u < 32; ++u) {
            float hvv = hcol[u];
#pragma unroll
            for (int o = 0; o < 16; ++o)
                a[o] = __builtin_fmaf(sWd[o * 32 + u], hvv, a[o]);
        }
        float rr = sBo[0];
#pragma unroll
        for (int o = 0; o < 16; ++o)
            rr = __builtin_fmaf(sWo[o], fmaxf(a[o], 0.0f), rr);
        out[bbase + lane] = fsig(rr);
    }
}

extern "C" void kernel_launch(void* const* d_in, const int* in_sizes, int n_in,
                              void* d_out, int out_size, void* d_ws, size_t ws_size,
                              hipStream_t stream) {
    const float* x    = (const float*)d_in[0];
    const float* Wih1 = (const float*)d_in[1];
    const float* Whh1 = (const float*)d_in[2];
    const float* bih1 = (const float*)d_in[3];
    const float* bhh1 = (const float*)d_in[4];
    const float* Wih2 = (const float*)d_in[5];
    const float* Whh2 = (const float*)d_in[6];
    const float* bih2 = (const float*)d_in[7];
    const float* bhh2 = (const float*)d_in[8];
    const float* Wd   = (const float*)d_in[9];
    const float* bd   = (const float*)d_in[10];
    const float* Wo   = (const float*)d_in[11];
    const float* bo   = (const float*)d_in[12];
    float* out = (float*)d_out;

    lstm_kernel<<<NBLOCKS, THREADS, 0, stream>>>(
        x, Wih1, Whh1, bih1, bhh1, Wih2, Whh2, bih2, bhh2, Wd, bd, Wo, bo, out);
}

// Round 6
// 307.766 us; speedup vs baseline: 1.5353x; 1.5353x over previous
//
#include <hip/hip_runtime.h>

// MomentumLSTM R6: single-bf16 weights (no hi/lo split), pre-scaled gate rows,
// 4 L1-waves (16 units) + 4 L2-waves (8 units) per 32-batch tile, lean registers
// (launch_bounds(512,4) targets <=128 regs -> 4 waves/SIMD).
// L1 bias rides in the x-frag (k=7 vs 1.0); L2 bias = f32 accumulator init.
// Gate rows pre-scaled by -log2e (i,f,o) / +2log2e (g) so MFMA outputs feed
// v_exp_f32 directly. h-frag exchange via small parity-double-buffered LDS;
// own-ktile B-frag built in-register via v_permlane32_swap then published.

using f32x16 = __attribute__((ext_vector_type(16))) float;
using s16x8  = __attribute__((ext_vector_type(8)))  short;
using uint2v = __attribute__((ext_vector_type(2)))  unsigned int;
typedef unsigned int uint;
typedef unsigned short ushort;

#define THREADS 512
#define NBLOCKS 1024
#define L2E 1.44269504f

__device__ __forceinline__ float fsig(float v) {
    float e = __builtin_amdgcn_exp2f(-L2E * v);
    return __builtin_amdgcn_rcpf(1.0f + e);
}
// Activation block for PRE-SCALED preacts: zi,zf,zo = -L2E*gate, zg = +2L2E*gate.
__device__ __forceinline__ void lstm_act_pre(float zi, float zf, float zg, float zo,
                                             float& cs, float& hv) {
    float ei = __builtin_amdgcn_exp2f(zi);
    float ef = __builtin_amdgcn_exp2f(zf);
    float eg = __builtin_amdgcn_exp2f(zg);
    float eo = __builtin_amdgcn_exp2f(zo);
    float ai = 1.0f + ei, af = 1.0f + ef;
    float r0 = __builtin_amdgcn_rcpf(ai * af);
    float iv = r0 * af, fv = r0 * ai;                 // sigmoid(i), sigmoid(f)
    float ag = 1.0f + eg, ao = 1.0f + eo;
    float r1 = __builtin_amdgcn_rcpf(ag * ao);
    float gv = __builtin_fmaf(-2.0f * r1, ao, 1.0f);  // tanh(g)
    float ov = r1 * ag;                               // sigmoid(o)
    float c = __builtin_fmaf(fv, cs, iv * gv);
    cs = c;
    float et = __builtin_amdgcn_exp2f((2.0f * L2E) * c);
    float tt = __builtin_fmaf(-2.0f, __builtin_amdgcn_rcpf(1.0f + et), 1.0f);
    hv = ov * tt;
}
__device__ __forceinline__ ushort bfhi(float w) {     // round-to-nearest-even bf16
    uint u = __builtin_bit_cast(uint, w);
    return (ushort)((u + 0x7fffu + ((u >> 16) & 1u)) >> 16);
}
__device__ __forceinline__ uint pkbf(float a, float b) {
    uint r;
    asm("v_cvt_pk_bf16_f32 %0, %1, %2" : "=v"(r) : "v"(a), "v"(b));
    return r;
}
__device__ __forceinline__ uint4 pack8(const ushort v[8]) {
    return make_uint4(v[0] | ((uint)v[1] << 16), v[2] | ((uint)v[3] << 16),
                      v[4] | ((uint)v[5] << 16), v[6] | ((uint)v[7] << 16));
}
#define MFMA32(a, b, c) \
    __builtin_amdgcn_mfma_f32_32x32x16_bf16(__builtin_bit_cast(s16x8, (a)), \
        __builtin_bit_cast(s16x8, (b)), (c), 0, 0, 0)
#define PLSWAP(a, b) __builtin_amdgcn_permlane32_swap((a), (b), false, false)

__global__ void __launch_bounds__(THREADS, 4) lstm_kernel(
    const float* __restrict__ x,
    const float* __restrict__ Wih1, const float* __restrict__ Whh1,
    const float* __restrict__ bih1, const float* __restrict__ bhh1,
    const float* __restrict__ Wih2, const float* __restrict__ Whh2,
    const float* __restrict__ bih2, const float* __restrict__ bhh2,
    const float* __restrict__ Wd, const float* __restrict__ bd,
    const float* __restrict__ Wo, const float* __restrict__ bo,
    float* __restrict__ out)
{
    __shared__ uint4 sH1[2][4][64];    // h1 B-frags [parity][ktile][lane]
    __shared__ uint4 sH2q[2][32][4];   // h2 packed  [parity][col][upair-quad]
    __shared__ uint4 sX[2][32];        // packed x   [parity][col]
    __shared__ float sWd[512];
    __shared__ float sBd[16], sWo[16], sBo[1];
    __shared__ float sHs[1024];        // head scratch [col][unit]

    const int tid = threadIdx.x;
    const int lane = tid & 63, wave = tid >> 6;
    const int hh = lane >> 5, n = lane & 31;
    const int bbase = blockIdx.x * 32;

    for (int i = tid; i < 512; i += THREADS) sWd[i] = Wd[i];
    if (tid < 16) { sBd[tid] = bd[tid]; sWo[tid] = Wo[tid]; }
    if (tid == 0) sBo[0] = bo[0];
    {
        uint4 z = make_uint4(0, 0, 0, 0);
        uint4* p1 = &sH1[0][0][0];
        for (int i = tid; i < 512; i += THREADS) p1[i] = z;
        uint4* p2 = &sH2q[0][0][0];
        for (int i = tid; i < 256; i += THREADS) p2[i] = z;
    }

    if (wave < 4) {
        // ================= L1 wave: h1 units [16w, 16w+16) =================
        const int w = wave;
        uint4 wr[8];    // Whh1 A-frags [mtile2][ktile4]
        uint4 xwf[2];   // Wih1+bias A-frags (weights in hh=0 k-half only)
#pragma unroll
        for (int m = 0; m < 2; ++m) {
            int gate = 2 * m + (n >> 4);
            int G = gate * 64 + 16 * w + (n & 15);
            float sc = (gate == 2) ? (2.0f * L2E) : (-L2E);
#pragma unroll
            for (int kt = 0; kt < 4; ++kt) {
                const float* src = Whh1 + G * 64 + kt * 16 + hh * 8;
                ushort v[8];
#pragma unroll
                for (int e = 0; e < 8; ++e) v[e] = bfhi(src[e] * sc);
                wr[m * 4 + kt] = pack8(v);
            }
            float b1 = (bih1[G] + bhh1[G]) * sc;
            ushort v[8];
#pragma unroll
            for (int e = 0; e < 8; ++e)
                v[e] = (hh == 0) ? bfhi(((e < 7) ? Wih1[G * 7 + e] * sc : b1)) : (ushort)0;
            xwf[m] = pack8(v);
        }
        float cst[8];
#pragma unroll
        for (int r = 0; r < 8; ++r) cst[r] = 0.f;
        __syncthreads();

        f32x16 Z;
#pragma unroll
        for (int i = 0; i < 16; ++i) Z[i] = 0.f;

        for (int t = 0; t < 60; ++t) {
            const int rp = (t + 1) & 1;
            uint4 xB = sX[t & 1][n];
            uint4 h0 = sH1[rp][0][lane];
            uint4 h1f = sH1[rp][1][lane];
            uint4 h2f = sH1[rp][2][lane];
            uint4 h3 = sH1[rp][3][lane];
            f32x16 cA = MFMA32(xwf[0], xB, Z);
            f32x16 cB = MFMA32(xwf[1], xB, Z);
            cA = MFMA32(wr[0], h0, cA);  cB = MFMA32(wr[4], h0, cB);
            cA = MFMA32(wr[1], h1f, cA); cB = MFMA32(wr[5], h1f, cB);
            cA = MFMA32(wr[2], h2f, cA); cB = MFMA32(wr[6], h2f, cB);
            cA = MFMA32(wr[3], h3, cA);  cB = MFMA32(wr[7], h3, cB);
            float hv[8];
#pragma unroll
            for (int r = 0; r < 8; ++r)
                lstm_act_pre(cA[r], cA[r + 8], cB[r], cB[r + 8], cst[r], hv[r]);
            uint Q00 = pkbf(hv[0], hv[1]), Q01 = pkbf(hv[4], hv[5]);
            uint Q10 = pkbf(hv[2], hv[3]), Q11 = pkbf(hv[6], hv[7]);
            uint2v sA = PLSWAP(Q00, Q01);
            uint2v sB = PLSWAP(Q10, Q11);
            sH1[t & 1][w][lane] = make_uint4(sA[0], sB[0], sA[1], sB[1]);
            __syncthreads();
        }
        __syncthreads();   // match L2's post-loop barrier
    } else {
        // ================= L2 wave: h2 units [8w2, 8w2+8) =================
        const int w2 = wave - 4;
        uint4 wih[4], whh[2];
        f32x16 bias2;
        {
            int gate = n >> 3;
            int G = gate * 32 + 8 * w2 + (n & 7);
            float sc = (gate == 2) ? (2.0f * L2E) : (-L2E);
#pragma unroll
            for (int kt = 0; kt < 4; ++kt) {
                const float* src = Wih2 + G * 64 + kt * 16 + hh * 8;
                ushort v[8];
#pragma unroll
                for (int e = 0; e < 8; ++e) v[e] = bfhi(src[e] * sc);
                wih[kt] = pack8(v);
            }
#pragma unroll
            for (int kt = 0; kt < 2; ++kt) {
                const float* src = Whh2 + G * 32 + kt * 16 + hh * 8;
                ushort v[8];
#pragma unroll
                for (int e = 0; e < 8; ++e) v[e] = bfhi(src[e] * sc);
                whh[kt] = pack8(v);
            }
#pragma unroll
            for (int r = 0; r < 16; ++r) {
                int row = (r & 3) + 8 * (r >> 2) + 4 * hh;
                int Gb = (row >> 3) * 32 + 8 * w2 + (row & 7);
                float scb = ((row >> 3) == 2) ? (2.0f * L2E) : (-L2E);
                bias2[r] = (bih2[Gb] + bhh2[Gb]) * scb;
            }
        }
        float cst[4];
#pragma unroll
        for (int s = 0; s < 4; ++s) cst[s] = 0.f;
        float hv[4];
        const float* xp = x + (size_t)(bbase + lane) * 420;
        const bool xload = (wave == 4) && (lane < 32);
        if (xload) {
            float x0[7];
#pragma unroll
            for (int d = 0; d < 7; ++d) x0[d] = xp[d];
            sX[0][lane] = make_uint4(pkbf(x0[0], x0[1]), pkbf(x0[2], x0[3]),
                                     pkbf(x0[4], x0[5]), pkbf(x0[6], 1.0f));
        }
        __syncthreads();

        for (int t = 0; t < 60; ++t) {
            float xr[7];
            if (xload && t < 59) {
#pragma unroll
                for (int d = 0; d < 7; ++d) xr[d] = xp[(t + 1) * 7 + d];
            }
            if (t > 0) {
                const int rp = (t + 1) & 1;      // parity of h1(t-1); write parity h2(t-1)
                uint4 h0 = sH1[rp][0][lane];
                uint4 h1f = sH1[rp][1][lane];
                uint4 h2f = sH1[rp][2][lane];
                uint4 h3 = sH1[rp][3][lane];
                uint4 g0 = sH2q[t & 1][n][hh];       // h2(t-2) ktile 0
                uint4 g1 = sH2q[t & 1][n][2 + hh];   // h2(t-2) ktile 1
                f32x16 c = bias2;
                c = MFMA32(wih[0], h0, c);
                c = MFMA32(wih[1], h1f, c);
                c = MFMA32(wih[2], h2f, c);
                c = MFMA32(wih[3], h3, c);
                c = MFMA32(whh[0], g0, c);
                c = MFMA32(whh[1], g1, c);
#pragma unroll
                for (int s = 0; s < 4; ++s)
                    lstm_act_pre(c[s], c[s + 4], c[s + 8], c[s + 12], cst[s], hv[s]);
                uint Qe = pkbf(hv[0], hv[1]), Qf = pkbf(hv[2], hv[3]);
                uint* p = (uint*)&sH2q[rp][n][0];
                *(uint2*)&p[4 * w2 + 2 * hh] = make_uint2(Qe, Qf);
            }
            if (xload && t < 59) {
                sX[(t + 1) & 1][lane] = make_uint4(pkbf(xr[0], xr[1]), pkbf(xr[2], xr[3]),
                                                   pkbf(xr[4], xr[5]), pkbf(xr[6], 1.0f));
            }
            __syncthreads();
        }
        // -------- final L2 step (t=59): h1(59)@parity1, h2(58)@parity0 --------
        {
            uint4 h0 = sH1[1][0][lane];
            uint4 h1f = sH1[1][1][lane];
            uint4 h2f = sH1[1][2][lane];
            uint4 h3 = sH1[1][3][lane];
            uint4 g0 = sH2q[0][n][hh];
            uint4 g1 = sH2q[0][n][2 + hh];
            f32x16 c = bias2;
            c = MFMA32(wih[0], h0, c);
            c = MFMA32(wih[1], h1f, c);
            c = MFMA32(wih[2], h2f, c);
            c = MFMA32(wih[3], h3, c);
            c = MFMA32(whh[0], g0, c);
            c = MFMA32(whh[1], g1, c);
#pragma unroll
            for (int s = 0; s < 4; ++s)
                lstm_act_pre(c[s], c[s + 4], c[s + 8], c[s + 12], cst[s], hv[s]);
#pragma unroll
            for (int s = 0; s < 4; ++s)
                sHs[n * 32 + 8 * w2 + 4 * hh + s] = hv[s];
        }
        __syncthreads();

        // ---------------- dense head (one wave) ----------------
        if (wave == 4 && lane < 32) {
            const float* hcol = sHs + lane * 32;
            float a[16];
#pragma unroll
            for (int o = 0; o < 16; ++o) a[o] = sBd[o];
#pragma unroll 4
            for (int u = 0; u < 32; ++u) {
                float hvv = hcol[u];
#pragma unroll
                for (int o = 0; o < 16; ++o)
                    a[o] = __builtin_fmaf(sWd[o * 32 + u], hvv, a[o]);
            }
            float rr = sBo[0];
#pragma unroll
            for (int o = 0; o < 16; ++o)
                rr = __builtin_fmaf(sWo[o], fmaxf(a[o], 0.0f), rr);
            out[bbase + lane] = fsig(rr);
        }
    }
}

extern "C" void kernel_launch(void* const* d_in, const int* in_sizes, int n_in,
                              void* d_out, int out_size, void* d_ws, size_t ws_size,
                              hipStream_t stream) {
    const float* x    = (const float*)d_in[0];
    const float* Wih1 = (const float*)d_in[1];
    const float* Whh1 = (const float*)d_in[2];
    const float* bih1 = (const float*)d_in[3];
    const float* bhh1 = (const float*)d_in[4];
    const float* Wih2 = (const float*)d_in[5];
    const float* Whh2 = (const float*)d_in[6];
    const float* bih2 = (const float*)d_in[7];
    const float* bhh2 = (const float*)d_in[8];
    const float* Wd   = (const float*)d_in[9];
    const float* bd   = (const float*)d_in[10];
    const float* Wo   = (const float*)d_in[11];
    const float* bo   = (const float*)d_in[12];
    float* out = (float*)d_out;

    lstm_kernel<<<NBLOCKS, THREADS, 0, stream>>>(
        x, Wih1, Whh1, bih1, bhh1, Wih2, Whh2, bih2, bhh2, Wd, bd, Wo, bo, out);
}